// Round 1
// baseline (379.522 us; speedup 1.0000x reference)
//
#include <hip/hip_runtime.h>
#include <math.h>

// Problem constants
#define BB 32
#define CC 122
#define TT 500
#define SS 13
#define WID 80
#define EMB 8
#define PROJ 1024
#define HID 768
#define TP 96          // pooled time length
#define EPSF 1e-5f
#define KP 9760        // conv2 flat K' = 122*80
#define KSPLIT 8       // 8 chunks x 8 c-pairs (c-pairs 61..63 zero/skip)
#define NBLK 256       // mega grid: 256 blocks == #CUs -> co-residency guaranteed
#define NTHR 384       // 6 waves
#define NT (NBLK * NTHR)

typedef float f32x4 __attribute__((ext_vector_type(4)));
typedef __bf16 bf16x8 __attribute__((ext_vector_type(8)));
typedef unsigned short u16x8 __attribute__((ext_vector_type(8)));
union BF8 { u16x8 u; bf16x8 b; };

// float -> bf16 bits, round-to-nearest-even
__device__ __forceinline__ unsigned short f2bf(float f) {
    union { float f; unsigned u; } v; v.f = f;
    unsigned r = v.u + 0x7FFFu + ((v.u >> 16) & 1u);
    return (unsigned short)(r >> 16);
}

__device__ __forceinline__ float eluf(float x) {
    return x > 0.f ? x : __expf(x) - 1.f;
}

// ---------------- workspace layout (float offsets) ----------------
#define OFF_E    ((size_t)0)            // oute (B,C,T) f32        1,952,000
#define OFF_XB   ((size_t)1952000)      // x_bf (B,128,512) bf16
#define OFF_WB   ((size_t)3000576)      // W_bf (S,512,512) bf16
#define OFF_W2P  ((size_t)4704512)      // w2p (80,9760) bf16
#define OFF_PART ((size_t)20086272)     // (KSPLIT,B,WID,TP) f32  (uses < old 16-split region)
#define OFF_Z    ((size_t)24018432)     // z_bf (B,HID) bf16
#define OFF_Z1   ((size_t)24030720)     // z1 (B,PROJ) f32
#define OFF_G    ((size_t)24063488)     // g_bf (B,PROJ) bf16
#define OFF_Y    ((size_t)24079872)     // y (B,PROJ) f32
#define OFF_W1B  ((size_t)24112640)     // w1b (PROJ,HID) bf16
#define OFF_W2B  ((size_t)24505856)     // w2b (PROJ,PROJ) bf16
#define OFF_WCB  ((size_t)25030144)     // wcb (80,32) bf16
#define OFF_B1F  ((size_t)25031424)     // (WID)
#define OFF_SC2  ((size_t)25031504)     // (WID)
#define OFF_SH2  ((size_t)25031584)     // (WID)
#define OFF_BAR  ((size_t)25031664)     // 8 x u32 barrier counters

// pack region sizes (float4 units unless noted)
#define NPK_X4  524288    // 32*128*512 /4
#define NPK_W4  851968    // 13*512*512 /4
#define NPK_W2  780800    // 80*9760 (scalar: scattered 2B writes)
#define NPK_M14 196608    // 1024*768 /4
#define NPK_M24 262144    // 1024*1024 /4

// ---------------- init: constants + barrier counters (1 block) ----------------
__global__ __launch_bounds__(128) void k_init(const float* __restrict__ conv1_w, const float* __restrict__ conv1_b,
                                              const float* __restrict__ g1, const float* __restrict__ b1,
                                              const float* __restrict__ m1, const float* __restrict__ v1,
                                              const float* __restrict__ conv2_b, const float* __restrict__ g2,
                                              const float* __restrict__ b2, const float* __restrict__ m2,
                                              const float* __restrict__ v2,
                                              unsigned short* __restrict__ wcb, float* __restrict__ bias1f,
                                              float* __restrict__ scale2, float* __restrict__ shift2f,
                                              unsigned* __restrict__ bar) {
    int o = threadIdx.x;
    if (o < WID) {
        float s1 = g1[o] * rsqrtf(v1[o] + EPSF);
        float sh1 = b1[o] - m1[o] * s1;
        #pragma unroll
        for (int d = 0; d < 21; d++) {
            int klo = d - 16; if (klo < 0) klo = 0;
            int khi = d;      if (khi > 4) khi = 4;
            float acc = 0.f;
            for (int k = klo; k <= khi; k++) acc += conv1_w[o*5 + k];
            wcb[o*32 + d] = f2bf(acc * s1 * (1.f/17.f));
        }
        #pragma unroll
        for (int d = 21; d < 32; d++) wcb[o*32 + d] = 0;
        bias1f[o] = conv1_b[o] * s1 + sh1;
        float s2 = g2[o] * rsqrtf(v2[o] + EPSF);
        scale2[o] = s2;
        shift2f[o] = conv2_b[o] * s2 + (b2[o] - m2[o] * s2);
    }
    if (o >= 96 && o < 104) bar[o - 96] = 0;
}

// ---------------- device-scope grid barrier (co-resident grid; timeout -> visible fail, no hang) --
__device__ __forceinline__ void gbar(unsigned* c) {
    __syncthreads();
    if (threadIdx.x == 0) {
        __threadfence();                       // flush this XCD's L2 (device-scope release)
        atomicAdd(c, 1u);                      // device-scope by default on CDNA
        long long t0 = clock64();
        while (__hip_atomic_load(c, __ATOMIC_ACQUIRE, __HIP_MEMORY_SCOPE_AGENT) < (unsigned)NBLK) {
            if (clock64() - t0 > 300000000LL) break;   // escape hatch: wrong answer beats deadlock
        }
        __threadfence();                       // acquire side: invalidate local caches
    }
    __syncthreads();
}

// ---------------- the mega-kernel: all 7 phases, 6 grid barriers ----------------
__global__ __launch_bounds__(NTHR) void k_mega(
        const float* __restrict__ x, const int* __restrict__ sid,
        const float* __restrict__ W_sub, const float* __restrict__ b_sub,
        const float* __restrict__ conv2_w,
        const float* __restrict__ mlp1_w, const float* __restrict__ mlp2_w,
        const float* __restrict__ pw, const float* __restrict__ pb,
        const float* __restrict__ m1bias, const float* __restrict__ m2bias,
        const float* __restrict__ lngw, const float* __restrict__ lnbw,
        unsigned short* __restrict__ xb, unsigned short* __restrict__ wb,
        unsigned short* __restrict__ w2p,
        unsigned short* __restrict__ w1b, unsigned short* __restrict__ w2b,
        const unsigned short* __restrict__ wcb, const float* __restrict__ b1f,
        const float* __restrict__ sc2, const float* __restrict__ sh2,
        float* __restrict__ oute, float* __restrict__ part,
        unsigned short* __restrict__ zbf, float* __restrict__ z1,
        unsigned short* __restrict__ gbf, float* __restrict__ y,
        unsigned* __restrict__ bar, float* __restrict__ out) {

    __shared__ union {
        struct { float e2[2][512]; unsigned short pt[96][164]; } fc;   // 35.5 KB
        struct { float ly[WID * 12]; float lw[EMB * WID]; } rp;        // 6.4 KB
        float accb[6][64][4];                                          // 6 KB
        struct { float ss[6]; float ssq[6]; float smu; float sinv; } ln;
    } sm;

    const int bid = blockIdx.x;
    const int tid = threadIdx.x;

    // ================= Phase P: pack (grid-stride, float4-vectorized) =================
    {
        unsigned gt = (unsigned)bid * NTHR + tid;
        for (unsigned u = gt; u < NPK_X4; u += NT) {               // x -> xb
            int s4 = u & 127, c = (u >> 7) & 127, b = u >> 14;
            float4 v = {0.f, 0.f, 0.f, 0.f};
            if (c < CC && s4 < 125)
                v = *(const float4*)(x + ((size_t)b * CC + c) * TT + 4 * s4);
            union { unsigned short s[4]; uint2 q; } pk;
            pk.s[0] = f2bf(v.x); pk.s[1] = f2bf(v.y); pk.s[2] = f2bf(v.z); pk.s[3] = f2bf(v.w);
            *(uint2*)(xb + 4 * (size_t)u) = pk.q;
        }
        for (unsigned u = gt; u < NPK_W4; u += NT) {               // W_sub -> wb
            int s4 = u & 127, t = (u >> 7) & 511, sub = u >> 16;
            float4 v = {0.f, 0.f, 0.f, 0.f};
            if (t < TT && s4 < 125)
                v = *(const float4*)(W_sub + ((size_t)sub * TT + t) * TT + 4 * s4);
            union { unsigned short s[4]; uint2 q; } pk;
            pk.s[0] = f2bf(v.x); pk.s[1] = f2bf(v.y); pk.s[2] = f2bf(v.z); pk.s[3] = f2bf(v.w);
            *(uint2*)(wb + 4 * (size_t)u) = pk.q;
        }
        for (unsigned j = gt; j < NPK_W2; j += NT) {               // conv2_w -> w2p (scatter)
            int o  = j / (WID * CC);
            int r  = j - o * (WID * CC);
            int op = r / CC, c = r - op * CC;
            w2p[(size_t)o * KP + (size_t)c * WID + op] = f2bf(conv2_w[j]);
        }
        for (unsigned u = gt; u < NPK_M14; u += NT) {              // mlp1_w -> w1b
            float4 v = *(const float4*)(mlp1_w + 4 * (size_t)u);
            union { unsigned short s[4]; uint2 q; } pk;
            pk.s[0] = f2bf(v.x); pk.s[1] = f2bf(v.y); pk.s[2] = f2bf(v.z); pk.s[3] = f2bf(v.w);
            *(uint2*)(w1b + 4 * (size_t)u) = pk.q;
        }
        for (unsigned u = gt; u < NPK_M24; u += NT) {              // mlp2_w -> w2b
            float4 v = *(const float4*)(mlp2_w + 4 * (size_t)u);
            union { unsigned short s[4]; uint2 q; } pk;
            pk.s[0] = f2bf(v.x); pk.s[1] = f2bf(v.y); pk.s[2] = f2bf(v.z); pk.s[3] = f2bf(v.w);
            *(uint2*)(w2b + 4 * (size_t)u) = pk.q;
        }
    }
    gbar(bar + 0);

    // ================= Phase E: subject einsum via MFMA (waves 0-3) =================
    {
        int t0 = (bid & 7) * 64, b = bid >> 3;
        if (tid < 256) {
            int s = sid[b];
            int w = tid >> 6, lr = tid & 15, lg = (tid >> 4) & 3;
            const unsigned short* A0 = xb + ((size_t)(b * 128 + w * 32 + lr)) * 512 + 8 * lg;
            const unsigned short* Bb = wb + (size_t)s * 262144 + 8 * lg;
            f32x4 acc[2][4] = {};
            for (int kb = 0; kb < 512; kb += 32) {
                BF8 a0, a1;
                a0.u = *(const u16x8*)(A0 + kb);
                a1.u = *(const u16x8*)(A0 + 16 * 512 + kb);
                #pragma unroll
                for (int nt = 0; nt < 4; nt++) {
                    BF8 bf; bf.u = *(const u16x8*)(Bb + (size_t)(t0 + nt * 16 + lr) * 512 + kb);
                    acc[0][nt] = __builtin_amdgcn_mfma_f32_16x16x32_bf16(a0.b, bf.b, acc[0][nt], 0, 0, 0);
                    acc[1][nt] = __builtin_amdgcn_mfma_f32_16x16x32_bf16(a1.b, bf.b, acc[1][nt], 0, 0, 0);
                }
            }
            const float* bg = b_sub + (size_t)s * TT;
            #pragma unroll
            for (int nt = 0; nt < 4; nt++) {
                int t = t0 + nt * 16 + lr;
                if (t < TT) {
                    float bias = bg[t];
                    #pragma unroll
                    for (int mt = 0; mt < 2; mt++) {
                        int crow = w * 32 + mt * 16 + 4 * lg;
                        #pragma unroll
                        for (int r = 0; r < 4; r++) {
                            int c = crow + r;
                            if (c < CC) oute[((size_t)b * CC + c) * TT + t] = acc[mt][nt][r] + bias;
                        }
                    }
                }
            }
        }
    }
    gbar(bar + 1);

    // ================= Phase F: fused FIR + conv2 (6 waves, 8 c-pairs/block) =================
    {
        int chunk = bid & 7, b = bid >> 3;
        int w = tid >> 6, l = tid & 63, lr = l & 15, lg = l >> 4;
        BF8 af[5]; float4 bf4[5];
        #pragma unroll
        for (int ot = 0; ot < 5; ot++) {
            af[ot].u = *(const u16x8*)(wcb + (ot * 16 + lr) * 32 + 8 * lg);
            bf4[ot] = *(const float4*)(b1f + ot * 16 + 4 * lg);
        }
        const unsigned short* Arow = w2p + (size_t)lr * KP + 8 * lg;
        f32x4 acc2[5] = {};
        for (int ci = 0; ci < 8; ci++) {
            int cp = chunk * 8 + ci;
            bool live = cp < 61;              // block-uniform
            if (live) {
                if (tid < 250) {
                    int cc = tid / 125, i = tid % 125;
                    ((float4*)sm.fc.e2[cc])[i] = ((const float4*)(oute + ((size_t)b * CC + cp * 2 + cc) * TT))[i];
                }
                if (tid >= 232 && tid < 256) {   // zero-pad e[500..511] both rows
                    int j = tid - 232; int cc = j / 12, i = 500 + (j % 12);
                    sm.fc.e2[cc][i] = 0.f;
                }
            }
            __syncthreads();                  // e2 ready; prev-iter pt reads done
            if (live) {
                #pragma unroll
                for (int cc = 0; cc < 2; cc++) {
                    int t = w * 16 + lr;
                    const float* ew = sm.fc.e2[cc] + 5 * t + 8 * lg;
                    BF8 bfr;
                    #pragma unroll
                    for (int j = 0; j < 8; j++) bfr.u[j] = f2bf(ew[j]);
                    f32x4 fa[5] = {};
                    #pragma unroll
                    for (int ot = 0; ot < 5; ot++)
                        fa[ot] = __builtin_amdgcn_mfma_f32_16x16x32_bf16(af[ot].b, bfr.b, fa[ot], 0, 0, 0);
                    #pragma unroll
                    for (int ot = 0; ot < 5; ot++) {
                        union { unsigned short s[4]; uint2 v; } pk;
                        #pragma unroll
                        for (int r = 0; r < 4; r++) pk.s[r] = f2bf(eluf(fa[ot][r] + bf4[ot][r]));
                        *(uint2*)&sm.fc.pt[t][cc * 80 + ot * 16 + 4 * lg] = pk.v;
                    }
                }
            }
            __syncthreads();                  // pt ready
            if (live) {
                #pragma unroll
                for (int kl = 0; kl < 5; kl++) {
                    BF8 bf; bf.u = *(const u16x8*)(&sm.fc.pt[w * 16 + lr][kl * 32 + lg * 8]);
                    int ko = cp * 160 + kl * 32;
                    #pragma unroll
                    for (int mt = 0; mt < 5; mt++) {
                        BF8 a; a.u = *(const u16x8*)(Arow + (size_t)mt * 16 * KP + ko);
                        acc2[mt] = __builtin_amdgcn_mfma_f32_16x16x32_bf16(a.b, bf.b, acc2[mt], 0, 0, 0);
                    }
                }
            }
        }
        float* pp = part + ((size_t)(chunk * BB + b) * WID) * TP;
        int t = w * 16 + lr;
        #pragma unroll
        for (int mt = 0; mt < 5; mt++) {
            int ob = mt * 16 + 4 * lg;
            #pragma unroll
            for (int r = 0; r < 4; r++)
                pp[(size_t)(ob + r) * TP + t] = acc2[mt][r];
        }
    }
    gbar(bar + 2);

    // ================= Phase R: reduce split-K + bn2 + elu + proj -> zbf =================
    {
        int tq = bid & 7, b = bid >> 3;     // 8 t-groups of 12
        int t0 = tq * 12;
        for (int i = tid; i < EMB * WID; i += NTHR) sm.rp.lw[i] = pw[i];
        for (int i = tid; i < WID * 12; i += NTHR) {
            int o = i / 12, tl = i - o * 12;
            float acc = 0.f;
            #pragma unroll
            for (int ks = 0; ks < KSPLIT; ks++)
                acc += part[(size_t)(ks * BB + b) * (WID * TP) + o * TP + t0 + tl];
            sm.rp.ly[o * 12 + tl] = eluf(acc * sc2[o] + sh2[o]);
        }
        __syncthreads();
        if (tid < 12 * EMB) {
            int e = tid & 7, tl = tid >> 3;
            float acc = pb[e];
            #pragma unroll 10
            for (int o = 0; o < WID; o++) acc = fmaf(sm.rp.ly[o * 12 + tl], sm.rp.lw[e * WID + o], acc);
            zbf[(size_t)b * HID + (t0 + tl) * EMB + e] = f2bf(acc);
        }
    }
    gbar(bar + 3);

    // ================= Phase M1: z1 = z @ w1^T + b; g = gelu(z1) (6-way K-split) =================
    if (bid < 128) {
        int cu = bid >> 1, rh = bid & 1;    // 16-col unit, row half
        int w = tid >> 6, l = tid & 63, lr = l & 15, lg = l >> 4;
        int pcol = cu * 16 + lr;
        const unsigned short* wr = w1b + (size_t)pcol * HID + w * 128 + 8 * lg;
        const unsigned short* za = zbf + (size_t)(rh * 16 + lr) * HID + w * 128 + 8 * lg;
        f32x4 acc = {};
        for (int kb = 0; kb < 128; kb += 32) {
            BF8 bf; bf.u = *(const u16x8*)(wr + kb);
            BF8 a;  a.u  = *(const u16x8*)(za + kb);
            acc = __builtin_amdgcn_mfma_f32_16x16x32_bf16(a.b, bf.b, acc, 0, 0, 0);
        }
        #pragma unroll
        for (int r = 0; r < 4; r++) sm.accb[w][l][r] = acc[r];
        __syncthreads();
        if (w == 0) {
            float bs = m1bias[pcol];
            #pragma unroll
            for (int r = 0; r < 4; r++) {
                int row = rh * 16 + 4 * lg + r;
                float v = bs;
                #pragma unroll
                for (int q = 0; q < 6; q++) v += sm.accb[q][l][r];
                z1[(size_t)row * PROJ + pcol] = v;
                gbf[(size_t)row * PROJ + pcol] = f2bf(0.5f * v * (1.f + erff(v * 0.70710678118654752f)));
            }
        }
    }
    gbar(bar + 4);

    // ================= Phase M2: y = z1 + G @ w2^T + b (4-way K-split, waves 0-3) ============
    if (bid < 128) {
        int cu = bid >> 1, rh = bid & 1;
        int w = tid >> 6, l = tid & 63, lr = l & 15, lg = l >> 4;
        int pc = cu * 16 + lr;
        if (tid < 256) {
            const unsigned short* wr = w2b + (size_t)pc * PROJ + w * 256 + 8 * lg;
            const unsigned short* ga = gbf + (size_t)(rh * 16 + lr) * PROJ + w * 256 + 8 * lg;
            f32x4 acc = {};
            for (int kb = 0; kb < 256; kb += 32) {
                BF8 bf; bf.u = *(const u16x8*)(wr + kb);
                BF8 a;  a.u  = *(const u16x8*)(ga + kb);
                acc = __builtin_amdgcn_mfma_f32_16x16x32_bf16(a.b, bf.b, acc, 0, 0, 0);
            }
            #pragma unroll
            for (int r = 0; r < 4; r++) sm.accb[w][l][r] = acc[r];
        }
        __syncthreads();
        if (tid < 64) {
            float bs = m2bias[pc];
            #pragma unroll
            for (int r = 0; r < 4; r++) {
                int row = rh * 16 + 4 * lg + r;
                float v = bs + z1[(size_t)row * PROJ + pc];
                #pragma unroll
                for (int q = 0; q < 4; q++) v += sm.accb[q][l][r];
                y[(size_t)row * PROJ + pc] = v;
            }
        }
    }
    gbar(bar + 5);

    // ================= Phase LN: LayerNorm over 1024 per row -> out =================
    if (bid < 32) {
        int b = bid;
        float4 v = {0.f, 0.f, 0.f, 0.f};
        float s = 0.f, sq = 0.f;
        if (tid < 256) {
            v = ((const float4*)(y + (size_t)b * PROJ))[tid];
            s  = v.x + v.y + v.z + v.w;
            sq = v.x*v.x + v.y*v.y + v.z*v.z + v.w*v.w;
        }
        #pragma unroll
        for (int off = 32; off > 0; off >>= 1) {
            s  += __shfl_down(s, off);
            sq += __shfl_down(sq, off);
        }
        int wv = tid >> 6, lane = tid & 63;
        if (lane == 0) { sm.ln.ss[wv] = s; sm.ln.ssq[wv] = sq; }
        __syncthreads();
        if (tid == 0) {
            float Sm = 0.f, Sq = 0.f;
            #pragma unroll
            for (int q = 0; q < 6; q++) { Sm += sm.ln.ss[q]; Sq += sm.ln.ssq[q]; }
            float mu = Sm * (1.f / PROJ);
            float var = Sq * (1.f / PROJ) - mu * mu;
            sm.ln.smu = mu;
            sm.ln.sinv = rsqrtf(var + EPSF);
        }
        __syncthreads();
        if (tid < 256) {
            float mu = sm.ln.smu, inv = sm.ln.sinv;
            float4 g4 = ((const float4*)lngw)[tid];
            float4 b4 = ((const float4*)lnbw)[tid];
            float4 o4;
            o4.x = (v.x - mu) * inv * g4.x + b4.x;
            o4.y = (v.y - mu) * inv * g4.y + b4.y;
            o4.z = (v.z - mu) * inv * g4.z + b4.z;
            o4.w = (v.w - mu) * inv * g4.w + b4.w;
            ((float4*)(out + (size_t)b * PROJ))[tid] = o4;
        }
    }
}

extern "C" void kernel_launch(void* const* d_in, const int* in_sizes, int n_in,
                              void* d_out, int out_size, void* d_ws, size_t ws_size,
                              hipStream_t stream) {
    const float* x        = (const float*)d_in[0];
    const int*   sid      = (const int*)  d_in[1];
    const float* W_sub    = (const float*)d_in[2];
    const float* b_sub    = (const float*)d_in[3];
    const float* conv1_w  = (const float*)d_in[4];
    const float* conv1_b  = (const float*)d_in[5];
    const float* bn1_g    = (const float*)d_in[6];
    const float* bn1_b    = (const float*)d_in[7];
    const float* bn1_m    = (const float*)d_in[8];
    const float* bn1_v    = (const float*)d_in[9];
    const float* conv2_w  = (const float*)d_in[10];
    const float* conv2_b  = (const float*)d_in[11];
    const float* bn2_g    = (const float*)d_in[12];
    const float* bn2_b    = (const float*)d_in[13];
    const float* bn2_m    = (const float*)d_in[14];
    const float* bn2_v    = (const float*)d_in[15];
    const float* proj_w   = (const float*)d_in[16];
    const float* proj_b   = (const float*)d_in[17];
    const float* mlp1_w   = (const float*)d_in[18];
    const float* mlp1_b   = (const float*)d_in[19];
    const float* mlp2_w   = (const float*)d_in[20];
    const float* mlp2_b   = (const float*)d_in[21];
    const float* ln_g     = (const float*)d_in[22];
    const float* ln_b     = (const float*)d_in[23];
    float* out = (float*)d_out;
    float* ws  = (float*)d_ws;

    float* ws_e    = ws + OFF_E;
    unsigned short* ws_xb  = (unsigned short*)(ws + OFF_XB);
    unsigned short* ws_wb  = (unsigned short*)(ws + OFF_WB);
    unsigned short* ws_w2p = (unsigned short*)(ws + OFF_W2P);
    float* ws_part = ws + OFF_PART;
    unsigned short* ws_zbf = (unsigned short*)(ws + OFF_Z);
    float* ws_z1   = ws + OFF_Z1;
    unsigned short* ws_gbf = (unsigned short*)(ws + OFF_G);
    float* ws_y    = ws + OFF_Y;
    unsigned short* ws_w1b = (unsigned short*)(ws + OFF_W1B);
    unsigned short* ws_w2b = (unsigned short*)(ws + OFF_W2B);
    unsigned short* ws_wcb = (unsigned short*)(ws + OFF_WCB);
    float* ws_b1f  = ws + OFF_B1F;
    float* ws_sc2  = ws + OFF_SC2;
    float* ws_sh2  = ws + OFF_SH2;
    unsigned* ws_bar = (unsigned*)(ws + OFF_BAR);

    hipLaunchKernelGGL(k_init, dim3(1), dim3(128), 0, stream,
                       conv1_w, conv1_b, bn1_g, bn1_b, bn1_m, bn1_v,
                       conv2_b, bn2_g, bn2_b, bn2_m, bn2_v,
                       ws_wcb, ws_b1f, ws_sc2, ws_sh2, ws_bar);

    hipLaunchKernelGGL(k_mega, dim3(NBLK), dim3(NTHR), 0, stream,
                       x, sid, W_sub, b_sub, conv2_w, mlp1_w, mlp2_w,
                       proj_w, proj_b, mlp1_b, mlp2_b, ln_g, ln_b,
                       ws_xb, ws_wb, ws_w2p, ws_w1b, ws_w2b,
                       ws_wcb, ws_b1f, ws_sc2, ws_sh2,
                       ws_e, ws_part, ws_zbf, ws_z1, ws_gbf, ws_y,
                       ws_bar, out);
}

// Round 2
// 223.395 us; speedup vs baseline: 1.6989x; 1.6989x over previous
//
#include <hip/hip_runtime.h>
#include <math.h>

// Problem constants
#define BB 32
#define CC 122
#define TT 500
#define SS 13
#define WID 80
#define EMB 8
#define PROJ 1024
#define HID 768
#define TP 96          // pooled time length
#define EPSF 1e-5f
#define KP 9760        // conv2 flat K' = 122*80
#define KSPLIT 16      // 16 chunks x 4 c-pairs (c-pairs 61..63 are zero/skip)
#define TAILBLK 128    // tail kernel grid (trivially co-resident)

typedef float f32x4 __attribute__((ext_vector_type(4)));
typedef __bf16 bf16x8 __attribute__((ext_vector_type(8)));
typedef unsigned short u16x8 __attribute__((ext_vector_type(8)));
union BF8 { u16x8 u; bf16x8 b; };

// float -> bf16 bits, round-to-nearest-even
__device__ __forceinline__ unsigned short f2bf(float f) {
    union { float f; unsigned u; } v; v.f = f;
    unsigned r = v.u + 0x7FFFu + ((v.u >> 16) & 1u);
    return (unsigned short)(r >> 16);
}

__device__ __forceinline__ float eluf(float x) {
    return x > 0.f ? x : __expf(x) - 1.f;
}

// ---------------- workspace layout (float offsets) ----------------
#define OFF_E    ((size_t)0)            // oute (B,C,T) f32        1,952,000
#define OFF_XB   ((size_t)1952000)      // x_bf (B,128,512) bf16
#define OFF_WB   ((size_t)3000576)      // W_bf (S,512,512) bf16
#define OFF_W2P  ((size_t)4704512)      // w2p (80,9760) bf16
#define OFF_PART ((size_t)20086272)     // (KSPLIT,B,WID,TP) f32
#define OFF_Z    ((size_t)24018432)     // z_bf (B,HID) bf16
#define OFF_Z1   ((size_t)24030720)     // z1 (B,PROJ) f32
#define OFF_G    ((size_t)24063488)     // g_bf (B,PROJ) bf16
#define OFF_Y    ((size_t)24079872)     // y (B,PROJ) f32
#define OFF_W1B  ((size_t)24112640)     // w1b (PROJ,HID) bf16
#define OFF_W2B  ((size_t)24505856)     // w2b (PROJ,PROJ) bf16
#define OFF_WCB  ((size_t)25030144)     // wcb (80,32) bf16
#define OFF_B1F  ((size_t)25031424)     // (WID)
#define OFF_SC2  ((size_t)25031504)     // (WID)
#define OFF_SH2  ((size_t)25031584)     // (WID)
#define OFF_BAR  ((size_t)25031664)     // 8 x u32 barrier counters

// pack region sizes (elements)
#define NPK_X  (2097152)   // 32*128*512
#define NPK_W  (3407872)   // 13*512*512
#define NPK_W2 (780800)    // 80*9760
#define NPK_M1 (786432)    // 1024*768
#define NPK_M2 (1048576)   // 1024*1024
#define NPK_TOT (NPK_X + NPK_W + NPK_W2 + NPK_M1 + NPK_M2)

// ---------------- pack (bf16 staging) + prep + barrier-zero (block 0) ----------------
__global__ __launch_bounds__(256) void k_pack(const float* __restrict__ x,
                                              const float* __restrict__ W_sub,
                                              const float* __restrict__ conv2_w,
                                              const float* __restrict__ mlp1_w,
                                              const float* __restrict__ mlp2_w,
                                              const float* __restrict__ conv1_w, const float* __restrict__ conv1_b,
                                              const float* __restrict__ g1, const float* __restrict__ b1,
                                              const float* __restrict__ m1, const float* __restrict__ v1,
                                              const float* __restrict__ conv2_b, const float* __restrict__ g2,
                                              const float* __restrict__ b2, const float* __restrict__ m2,
                                              const float* __restrict__ v2,
                                              unsigned short* __restrict__ xb,
                                              unsigned short* __restrict__ wb,
                                              unsigned short* __restrict__ w2p,
                                              unsigned short* __restrict__ w1b,
                                              unsigned short* __restrict__ w2b,
                                              unsigned short* __restrict__ wcb, float* __restrict__ bias1f,
                                              float* __restrict__ scale2, float* __restrict__ shift2f,
                                              unsigned* __restrict__ bar) {
    if (blockIdx.x == 0) {
        int o = threadIdx.x;
        if (o < WID) {
            float s1 = g1[o] * rsqrtf(v1[o] + EPSF);
            float sh1 = b1[o] - m1[o] * s1;
            #pragma unroll
            for (int d = 0; d < 21; d++) {
                int klo = d - 16; if (klo < 0) klo = 0;
                int khi = d;      if (khi > 4) khi = 4;
                float acc = 0.f;
                for (int k = klo; k <= khi; k++) acc += conv1_w[o*5 + k];
                wcb[o*32 + d] = f2bf(acc * s1 * (1.f/17.f));
            }
            #pragma unroll
            for (int d = 21; d < 32; d++) wcb[o*32 + d] = 0;
            bias1f[o] = conv1_b[o] * s1 + sh1;
            float s2 = g2[o] * rsqrtf(v2[o] + EPSF);
            scale2[o] = s2;
            shift2f[o] = conv2_b[o] * s2 + (b2[o] - m2[o] * s2);
        }
        if (o >= 96 && o < 104) bar[o - 96] = 0;   // zero tail-kernel barrier counters
    }
    size_t idx = (size_t)blockIdx.x * 256 + threadIdx.x;
    if (idx >= (size_t)NPK_TOT) return;
    if (idx < NPK_X) {
        int s = idx & 511, c = (idx >> 9) & 127, b = idx >> 16;
        float v = (c < CC && s < TT) ? x[((size_t)b * CC + c) * TT + s] : 0.f;
        xb[idx] = f2bf(v);
    } else if (idx < NPK_X + NPK_W) {
        size_t j = idx - NPK_X;
        int s = j & 511, t = (j >> 9) & 511, sub = j >> 18;
        float v = (t < TT && s < TT) ? W_sub[((size_t)sub * TT + t) * TT + s] : 0.f;
        wb[j] = f2bf(v);
    } else if (idx < NPK_X + NPK_W + NPK_W2) {
        size_t j = idx - NPK_X - NPK_W;
        int o  = (int)(j / (WID * CC));
        int r  = (int)(j % (WID * CC));
        int op = r / CC, c = r % CC;
        w2p[(size_t)o * KP + (size_t)c * WID + op] = f2bf(conv2_w[j]);
    } else if (idx < NPK_X + NPK_W + NPK_W2 + NPK_M1) {
        size_t j = idx - NPK_X - NPK_W - NPK_W2;
        w1b[j] = f2bf(mlp1_w[j]);
    } else {
        size_t j = idx - NPK_X - NPK_W - NPK_W2 - NPK_M1;
        w2b[j] = f2bf(mlp2_w[j]);
    }
}

// ---------------- subject einsum via MFMA bf16 (512 thr: 8 waves, 2/SIMD) ----------------
__global__ __launch_bounds__(512) void k_einsum(const unsigned short* __restrict__ xb,
                                                const unsigned short* __restrict__ wb,
                                                const int* __restrict__ sid,
                                                const float* __restrict__ b_sub,
                                                float* __restrict__ oute) {
    int t0 = blockIdx.x * 64, b = blockIdx.y;
    int s = sid[b];
    int tid = threadIdx.x, w = tid >> 6, lr = tid & 15, lg = (tid >> 4) & 3;
    // wave w owns C-rows [w*16, w*16+16)
    const unsigned short* A0 = xb + ((size_t)(b * 128 + w * 16 + lr)) * 512 + 8 * lg;
    const unsigned short* Bb = wb + (size_t)s * 262144 + 8 * lg;
    f32x4 acc[4] = {};
    for (int kb = 0; kb < 512; kb += 32) {
        BF8 a0;
        a0.u = *(const u16x8*)(A0 + kb);
        #pragma unroll
        for (int nt = 0; nt < 4; nt++) {
            BF8 bf; bf.u = *(const u16x8*)(Bb + (size_t)(t0 + nt * 16 + lr) * 512 + kb);
            acc[nt] = __builtin_amdgcn_mfma_f32_16x16x32_bf16(a0.b, bf.b, acc[nt], 0, 0, 0);
        }
    }
    const float* bg = b_sub + (size_t)s * TT;
    #pragma unroll
    for (int nt = 0; nt < 4; nt++) {
        int t = t0 + nt * 16 + lr;
        if (t < TT) {
            float bias = bg[t];
            int crow = w * 16 + 4 * lg;
            #pragma unroll
            for (int r = 0; r < 4; r++) {
                int c = crow + r;
                if (c < CC) oute[((size_t)b * CC + c) * TT + t] = acc[nt][r] + bias;
            }
        }
    }
}

// ---------------- fused FIR+conv2: p never touches HBM (round-0 verbatim) ----------------
__global__ __launch_bounds__(384) void k_fc(const float* __restrict__ oute,
                                            const unsigned short* __restrict__ wcb,
                                            const float* __restrict__ b1f,
                                            const unsigned short* __restrict__ w2p,
                                            float* __restrict__ part) {
    __shared__ float e2[2][512];
    __shared__ unsigned short pt[96][164];
    int chunk = blockIdx.x, b = blockIdx.y;
    int tid = threadIdx.x, w = tid >> 6, l = tid & 63, lr = l & 15, lg = l >> 4;
    BF8 af[5]; float4 bf4[5];
    #pragma unroll
    for (int ot = 0; ot < 5; ot++) {
        af[ot].u = *(const u16x8*)(wcb + (ot * 16 + lr) * 32 + 8 * lg);
        bf4[ot] = *(const float4*)(b1f + ot * 16 + 4 * lg);
    }
    const unsigned short* Arow = w2p + (size_t)lr * KP + 8 * lg;
    f32x4 acc2[5] = {};
    for (int ci = 0; ci < 4; ci++) {
        int cp = chunk * 4 + ci;
        bool live = cp < 61;              // block-uniform
        if (live) {
            if (tid < 250) {
                int cc = tid / 125, i = tid % 125;
                ((float4*)e2[cc])[i] = ((const float4*)(oute + ((size_t)b * CC + cp * 2 + cc) * TT))[i];
            }
            if (tid >= 232 && tid < 256) {   // zero-pad e[500..511] both rows
                int j = tid - 232; int cc = j / 12, i = 500 + (j % 12);
                e2[cc][i] = 0.f;
            }
        }
        __syncthreads();                  // e2 ready; prev-iter pt reads done
        if (live) {
            #pragma unroll
            for (int cc = 0; cc < 2; cc++) {
                int t = w * 16 + lr;
                const float* ew = e2[cc] + 5 * t + 8 * lg;
                BF8 bfr;
                #pragma unroll
                for (int j = 0; j < 8; j++) bfr.u[j] = f2bf(ew[j]);
                f32x4 fa[5] = {};
                #pragma unroll
                for (int ot = 0; ot < 5; ot++)
                    fa[ot] = __builtin_amdgcn_mfma_f32_16x16x32_bf16(af[ot].b, bfr.b, fa[ot], 0, 0, 0);
                #pragma unroll
                for (int ot = 0; ot < 5; ot++) {
                    union { unsigned short s[4]; uint2 v; } pk;
                    #pragma unroll
                    for (int r = 0; r < 4; r++) pk.s[r] = f2bf(eluf(fa[ot][r] + bf4[ot][r]));
                    *(uint2*)&pt[t][cc * 80 + ot * 16 + 4 * lg] = pk.v;
                }
            }
        }
        __syncthreads();                  // pt ready
        if (live) {
            #pragma unroll
            for (int kl = 0; kl < 5; kl++) {
                BF8 bf; bf.u = *(const u16x8*)(&pt[w * 16 + lr][kl * 32 + lg * 8]);
                int ko = cp * 160 + kl * 32;
                #pragma unroll
                for (int mt = 0; mt < 5; mt++) {
                    BF8 a; a.u = *(const u16x8*)(Arow + (size_t)mt * 16 * KP + ko);
                    acc2[mt] = __builtin_amdgcn_mfma_f32_16x16x32_bf16(a.b, bf.b, acc2[mt], 0, 0, 0);
                }
            }
        }
    }
    float* pp = part + ((size_t)(chunk * BB + b) * WID) * TP;
    int t = w * 16 + lr;
    #pragma unroll
    for (int mt = 0; mt < 5; mt++) {
        int ob = mt * 16 + 4 * lg;
        #pragma unroll
        for (int r = 0; r < 4; r++)
            pp[(size_t)(ob + r) * TP + t] = acc2[mt][r];
    }
}

// ---------------- device-scope grid barrier (co-resident grid; timeout -> visible fail) ----
__device__ __forceinline__ void gbar(unsigned* c, unsigned target) {
    __syncthreads();
    if (threadIdx.x == 0) {
        __threadfence();
        atomicAdd(c, 1u);
        long long t0 = clock64();
        while (__hip_atomic_load(c, __ATOMIC_ACQUIRE, __HIP_MEMORY_SCOPE_AGENT) < target) {
            if (clock64() - t0 > 300000000LL) break;   // escape hatch: wrong answer beats deadlock
        }
        __threadfence();
    }
    __syncthreads();
}

// ---------------- tail: reduce+proj -> mlp1 -> mlp2 -> LN, 3 grid barriers ----------------
// 128 blocks x 256 thr, ~10.3KB LDS -> trivially co-resident (0.5 blocks/CU).
__global__ __launch_bounds__(256) void k_tail(const float* __restrict__ part,
                                              const float* __restrict__ sc2,
                                              const float* __restrict__ sh2,
                                              const float* __restrict__ pw,
                                              const float* __restrict__ pb,
                                              const unsigned short* __restrict__ w1b,
                                              const float* __restrict__ m1bias,
                                              const unsigned short* __restrict__ w2b,
                                              const float* __restrict__ m2bias,
                                              const float* __restrict__ lngw,
                                              const float* __restrict__ lnbw,
                                              unsigned short* __restrict__ zbf,
                                              float* __restrict__ z1,
                                              unsigned short* __restrict__ gbf,
                                              float* __restrict__ y,
                                              unsigned* __restrict__ bar,
                                              float* __restrict__ out) {
    __shared__ union {
        struct { float ly[WID * 24]; float lw[EMB * WID]; } rp;   // 10.24 KB
        float accb[4][64][4];                                     // 4 KB
        struct { float ss[4]; float ssq[4]; float smu; float sinv; } ln;
    } sm;
    const int bid = blockIdx.x;
    const int tid = threadIdx.x;

    // ---- Phase R: reduce split-K + bn2 + elu + proj -> zbf (4 tq x 32 b) ----
    {
        int tq = bid >> 5, b = bid & 31;
        int t0 = tq * 24;
        for (int i = tid; i < EMB * WID; i += 256) sm.rp.lw[i] = pw[i];
        for (int i = tid; i < WID * 24; i += 256) {
            int o = i / 24, tl = i - o * 24;
            float acc = 0.f;
            #pragma unroll
            for (int ks = 0; ks < KSPLIT; ks++)
                acc += part[(size_t)(ks * BB + b) * (WID * TP) + o * TP + t0 + tl];
            sm.rp.ly[o * 24 + tl] = eluf(acc * sc2[o] + sh2[o]);
        }
        __syncthreads();
        if (tid < 24 * EMB) {
            int e = tid & 7, tl = tid >> 3;
            float acc = pb[e];
            #pragma unroll 10
            for (int o = 0; o < WID; o++) acc = fmaf(sm.rp.ly[o * 24 + tl], sm.rp.lw[e * WID + o], acc);
            zbf[(size_t)b * HID + (t0 + tl) * EMB + e] = f2bf(acc);
        }
    }
    gbar(bar + 0, TAILBLK);

    // ---- Phase M1: z1 = z @ w1^T + b; g = gelu(z1). 64 col-units x 2 row-halves ----
    {
        int cu = bid >> 1, rh = bid & 1;
        int w = tid >> 6, l = tid & 63, lr = l & 15, lg = l >> 4;
        int pcol = cu * 16 + lr;
        const unsigned short* wr = w1b + (size_t)pcol * HID + w * 192 + 8 * lg;
        const unsigned short* za = zbf + (size_t)(rh * 16 + lr) * HID + w * 192 + 8 * lg;
        f32x4 acc = {};
        #pragma unroll
        for (int kb = 0; kb < 192; kb += 32) {
            BF8 bf; bf.u = *(const u16x8*)(wr + kb);
            BF8 a;  a.u  = *(const u16x8*)(za + kb);
            acc = __builtin_amdgcn_mfma_f32_16x16x32_bf16(a.b, bf.b, acc, 0, 0, 0);
        }
        #pragma unroll
        for (int r = 0; r < 4; r++) sm.accb[w][l][r] = acc[r];
        __syncthreads();
        if (w == 0) {
            float bs = m1bias[pcol];
            #pragma unroll
            for (int r = 0; r < 4; r++) {
                int row = rh * 16 + 4 * lg + r;
                float v = bs;
                #pragma unroll
                for (int q = 0; q < 4; q++) v += sm.accb[q][l][r];
                z1[(size_t)row * PROJ + pcol] = v;
                gbf[(size_t)row * PROJ + pcol] = f2bf(0.5f * v * (1.f + erff(v * 0.70710678118654752f)));
            }
        }
    }
    gbar(bar + 1, TAILBLK);

    // ---- Phase M2: y = z1 + G @ w2^T + b. 64 col-units x 2 row-halves ----
    {
        int cu = bid >> 1, rh = bid & 1;
        int w = tid >> 6, l = tid & 63, lr = l & 15, lg = l >> 4;
        int pc = cu * 16 + lr;
        const unsigned short* wr = w2b + (size_t)pc * PROJ + w * 256 + 8 * lg;
        const unsigned short* ga = gbf + (size_t)(rh * 16 + lr) * PROJ + w * 256 + 8 * lg;
        f32x4 acc = {};
        #pragma unroll
        for (int kb = 0; kb < 256; kb += 32) {
            BF8 bf; bf.u = *(const u16x8*)(wr + kb);
            BF8 a;  a.u  = *(const u16x8*)(ga + kb);
            acc = __builtin_amdgcn_mfma_f32_16x16x32_bf16(a.b, bf.b, acc, 0, 0, 0);
        }
        #pragma unroll
        for (int r = 0; r < 4; r++) sm.accb[w][l][r] = acc[r];
        __syncthreads();
        if (w == 0) {
            float bs = m2bias[pc];
            #pragma unroll
            for (int r = 0; r < 4; r++) {
                int row = rh * 16 + 4 * lg + r;
                float v = bs + z1[(size_t)row * PROJ + pc];
                #pragma unroll
                for (int q = 0; q < 4; q++) v += sm.accb[q][l][r];
                y[(size_t)row * PROJ + pc] = v;
            }
        }
    }
    gbar(bar + 2, TAILBLK);

    // ---- Phase LN: LayerNorm over 1024 per row -> out (32 blocks active) ----
    if (bid < BB) {
        int b = bid;
        const float4* yr = (const float4*)(y + (size_t)b * PROJ);
        float4 v = yr[tid];
        float s  = v.x + v.y + v.z + v.w;
        float sq = v.x*v.x + v.y*v.y + v.z*v.z + v.w*v.w;
        #pragma unroll
        for (int off = 32; off > 0; off >>= 1) {
            s  += __shfl_down(s, off);
            sq += __shfl_down(sq, off);
        }
        int wv = tid >> 6, lane = tid & 63;
        if (lane == 0) { sm.ln.ss[wv] = s; sm.ln.ssq[wv] = sq; }
        __syncthreads();
        if (tid == 0) {
            float Sm = sm.ln.ss[0] + sm.ln.ss[1] + sm.ln.ss[2] + sm.ln.ss[3];
            float Sq = sm.ln.ssq[0] + sm.ln.ssq[1] + sm.ln.ssq[2] + sm.ln.ssq[3];
            float mu = Sm * (1.f / PROJ);
            float var = Sq * (1.f / PROJ) - mu * mu;
            sm.ln.smu = mu;
            sm.ln.sinv = rsqrtf(var + EPSF);
        }
        __syncthreads();
        float mu = sm.ln.smu, inv = sm.ln.sinv;
        float4 g4 = ((const float4*)lngw)[tid];
        float4 b4 = ((const float4*)lnbw)[tid];
        float4 o4;
        o4.x = (v.x - mu) * inv * g4.x + b4.x;
        o4.y = (v.y - mu) * inv * g4.y + b4.y;
        o4.z = (v.z - mu) * inv * g4.z + b4.z;
        o4.w = (v.w - mu) * inv * g4.w + b4.w;
        ((float4*)(out + (size_t)b * PROJ))[tid] = o4;
    }
}

extern "C" void kernel_launch(void* const* d_in, const int* in_sizes, int n_in,
                              void* d_out, int out_size, void* d_ws, size_t ws_size,
                              hipStream_t stream) {
    const float* x        = (const float*)d_in[0];
    const int*   sid      = (const int*)  d_in[1];
    const float* W_sub    = (const float*)d_in[2];
    const float* b_sub    = (const float*)d_in[3];
    const float* conv1_w  = (const float*)d_in[4];
    const float* conv1_b  = (const float*)d_in[5];
    const float* bn1_g    = (const float*)d_in[6];
    const float* bn1_b    = (const float*)d_in[7];
    const float* bn1_m    = (const float*)d_in[8];
    const float* bn1_v    = (const float*)d_in[9];
    const float* conv2_w  = (const float*)d_in[10];
    const float* conv2_b  = (const float*)d_in[11];
    const float* bn2_g    = (const float*)d_in[12];
    const float* bn2_b    = (const float*)d_in[13];
    const float* bn2_m    = (const float*)d_in[14];
    const float* bn2_v    = (const float*)d_in[15];
    const float* proj_w   = (const float*)d_in[16];
    const float* proj_b   = (const float*)d_in[17];
    const float* mlp1_w   = (const float*)d_in[18];
    const float* mlp1_b   = (const float*)d_in[19];
    const float* mlp2_w   = (const float*)d_in[20];
    const float* mlp2_b   = (const float*)d_in[21];
    const float* ln_g     = (const float*)d_in[22];
    const float* ln_b     = (const float*)d_in[23];
    float* out = (float*)d_out;
    float* ws  = (float*)d_ws;

    float* ws_e    = ws + OFF_E;
    unsigned short* ws_xb  = (unsigned short*)(ws + OFF_XB);
    unsigned short* ws_wb  = (unsigned short*)(ws + OFF_WB);
    unsigned short* ws_w2p = (unsigned short*)(ws + OFF_W2P);
    float* ws_part = ws + OFF_PART;
    unsigned short* ws_zbf = (unsigned short*)(ws + OFF_Z);
    float* ws_z1   = ws + OFF_Z1;
    unsigned short* ws_gbf = (unsigned short*)(ws + OFF_G);
    float* ws_y    = ws + OFF_Y;
    unsigned short* ws_w1b = (unsigned short*)(ws + OFF_W1B);
    unsigned short* ws_w2b = (unsigned short*)(ws + OFF_W2B);
    unsigned short* ws_wcb = (unsigned short*)(ws + OFF_WCB);
    float* ws_b1f  = ws + OFF_B1F;
    float* ws_sc2  = ws + OFF_SC2;
    float* ws_sh2  = ws + OFF_SH2;
    unsigned* ws_bar = (unsigned*)(ws + OFF_BAR);

    hipLaunchKernelGGL(k_pack, dim3((NPK_TOT + 255) / 256), dim3(256), 0, stream,
                       x, W_sub, conv2_w, mlp1_w, mlp2_w,
                       conv1_w, conv1_b, bn1_g, bn1_b, bn1_m, bn1_v,
                       conv2_b, bn2_g, bn2_b, bn2_m, bn2_v,
                       ws_xb, ws_wb, ws_w2p, ws_w1b, ws_w2b,
                       ws_wcb, ws_b1f, ws_sc2, ws_sh2, ws_bar);

    hipLaunchKernelGGL(k_einsum, dim3(8, BB), dim3(512), 0, stream,
                       ws_xb, ws_wb, sid, b_sub, ws_e);

    hipLaunchKernelGGL(k_fc, dim3(KSPLIT, BB), dim3(384), 0, stream,
                       ws_e, ws_wcb, ws_b1f, ws_w2p, ws_part);

    hipLaunchKernelGGL(k_tail, dim3(TAILBLK), dim3(256), 0, stream,
                       ws_part, ws_sc2, ws_sh2, proj_w, proj_b,
                       ws_w1b, mlp1_b, ws_w2b, mlp2_b, ln_g, ln_b,
                       ws_zbf, ws_z1, ws_gbf, ws_y, ws_bar, out);
}

// Round 3
// 200.733 us; speedup vs baseline: 1.8907x; 1.1129x over previous
//
#include <hip/hip_runtime.h>
#include <math.h>

// Problem constants
#define BB 32
#define CC 122
#define TT 500
#define SS 13
#define WID 80
#define EMB 8
#define PROJ 1024
#define HID 768
#define TP 96          // pooled time length
#define EPSF 1e-5f
#define KP 9760        // conv2 flat K' = 122*80
#define KSPLIT 16      // 16 chunks x 4 c-pairs (c-pairs 61..63 are zero/skip)

typedef float f32x4 __attribute__((ext_vector_type(4)));
typedef __bf16 bf16x8 __attribute__((ext_vector_type(8)));
typedef unsigned short u16x8 __attribute__((ext_vector_type(8)));
union BF8 { u16x8 u; bf16x8 b; };

// float -> bf16 bits, round-to-nearest-even
__device__ __forceinline__ unsigned short f2bf(float f) {
    union { float f; unsigned u; } v; v.f = f;
    unsigned r = v.u + 0x7FFFu + ((v.u >> 16) & 1u);
    return (unsigned short)(r >> 16);
}

__device__ __forceinline__ float eluf(float x) {
    return x > 0.f ? x : __expf(x) - 1.f;
}

// ---------------- workspace layout (float offsets) ----------------
#define OFF_E    ((size_t)0)            // oute (B,C,T) f32        1,952,000
#define OFF_XB   ((size_t)1952000)      // x_bf (B,128,512) bf16
#define OFF_WB   ((size_t)3000576)      // W_bf (S,512,512) bf16
#define OFF_W2P  ((size_t)4704512)      // w2p (80,9760) bf16
#define OFF_PART ((size_t)20086272)     // (KSPLIT,B,WID,TP) f32
#define OFF_Z    ((size_t)24018432)     // z_bf (B,HID) bf16
#define OFF_Z1   ((size_t)24030720)     // z1 (B,PROJ) f32
#define OFF_G    ((size_t)24063488)     // g_bf (B,PROJ) bf16
#define OFF_Y    ((size_t)24079872)     // y (B,PROJ) f32
#define OFF_W1B  ((size_t)24112640)     // w1b (PROJ,HID) bf16
#define OFF_W2B  ((size_t)24505856)     // w2b (PROJ,PROJ) bf16
#define OFF_WCB  ((size_t)25030144)     // wcb (80,32) bf16
#define OFF_B1F  ((size_t)25031424)     // (WID)
#define OFF_SC2  ((size_t)25031504)     // (WID)
#define OFF_SH2  ((size_t)25031584)     // (WID)

// pack region sizes (elements)
#define NPK_X  (2097152)   // 32*128*512
#define NPK_W  (3407872)   // 13*512*512
#define NPK_W2 (780800)    // 80*9760
#define NPK_M1 (786432)    // 1024*768
#define NPK_M2 (1048576)   // 1024*1024
#define NPK_TOT (NPK_X + NPK_W + NPK_W2 + NPK_M1 + NPK_M2)

// ---------------- pack (bf16 staging) + prep (block 0) ----------------
__global__ __launch_bounds__(256) void k_pack(const float* __restrict__ x,
                                              const float* __restrict__ W_sub,
                                              const float* __restrict__ conv2_w,
                                              const float* __restrict__ mlp1_w,
                                              const float* __restrict__ mlp2_w,
                                              const float* __restrict__ conv1_w, const float* __restrict__ conv1_b,
                                              const float* __restrict__ g1, const float* __restrict__ b1,
                                              const float* __restrict__ m1, const float* __restrict__ v1,
                                              const float* __restrict__ conv2_b, const float* __restrict__ g2,
                                              const float* __restrict__ b2, const float* __restrict__ m2,
                                              const float* __restrict__ v2,
                                              unsigned short* __restrict__ xb,
                                              unsigned short* __restrict__ wb,
                                              unsigned short* __restrict__ w2p,
                                              unsigned short* __restrict__ w1b,
                                              unsigned short* __restrict__ w2b,
                                              unsigned short* __restrict__ wcb, float* __restrict__ bias1f,
                                              float* __restrict__ scale2, float* __restrict__ shift2f) {
    if (blockIdx.x == 0) {
        int o = threadIdx.x;
        if (o < WID) {
            float s1 = g1[o] * rsqrtf(v1[o] + EPSF);
            float sh1 = b1[o] - m1[o] * s1;
            #pragma unroll
            for (int d = 0; d < 21; d++) {
                int klo = d - 16; if (klo < 0) klo = 0;
                int khi = d;      if (khi > 4) khi = 4;
                float acc = 0.f;
                for (int k = klo; k <= khi; k++) acc += conv1_w[o*5 + k];
                wcb[o*32 + d] = f2bf(acc * s1 * (1.f/17.f));
            }
            #pragma unroll
            for (int d = 21; d < 32; d++) wcb[o*32 + d] = 0;
            bias1f[o] = conv1_b[o] * s1 + sh1;
            float s2 = g2[o] * rsqrtf(v2[o] + EPSF);
            scale2[o] = s2;
            shift2f[o] = conv2_b[o] * s2 + (b2[o] - m2[o] * s2);
        }
    }
    size_t idx = (size_t)blockIdx.x * 256 + threadIdx.x;
    if (idx >= (size_t)NPK_TOT) return;
    if (idx < NPK_X) {
        int s = idx & 511, c = (idx >> 9) & 127, b = idx >> 16;
        float v = (c < CC && s < TT) ? x[((size_t)b * CC + c) * TT + s] : 0.f;
        xb[idx] = f2bf(v);
    } else if (idx < NPK_X + NPK_W) {
        size_t j = idx - NPK_X;
        int s = j & 511, t = (j >> 9) & 511, sub = j >> 18;
        float v = (t < TT && s < TT) ? W_sub[((size_t)sub * TT + t) * TT + s] : 0.f;
        wb[j] = f2bf(v);
    } else if (idx < NPK_X + NPK_W + NPK_W2) {
        size_t j = idx - NPK_X - NPK_W;
        int o  = (int)(j / (WID * CC));
        int r  = (int)(j % (WID * CC));
        int op = r / CC, c = r % CC;
        w2p[(size_t)o * KP + (size_t)c * WID + op] = f2bf(conv2_w[j]);
    } else if (idx < NPK_X + NPK_W + NPK_W2 + NPK_M1) {
        size_t j = idx - NPK_X - NPK_W - NPK_W2;
        w1b[j] = f2bf(mlp1_w[j]);
    } else {
        size_t j = idx - NPK_X - NPK_W - NPK_W2 - NPK_M1;
        w2b[j] = f2bf(mlp2_w[j]);
    }
}

// ---------------- subject einsum via MFMA bf16 ----------------
// 512 blocks (16 t-tiles x 32 b) x 256 thr -> 2 blocks/CU, 2 waves/SIMD.
// Same FLOPs and per-block B redundancy as round-0; doubled latency hiding.
__global__ __launch_bounds__(256) void k_einsum(const unsigned short* __restrict__ xb,
                                                const unsigned short* __restrict__ wb,
                                                const int* __restrict__ sid,
                                                const float* __restrict__ b_sub,
                                                float* __restrict__ oute) {
    int t0 = blockIdx.x * 32, b = blockIdx.y;
    int s = sid[b];
    int tid = threadIdx.x, w = tid >> 6, lr = tid & 15, lg = (tid >> 4) & 3;
    const unsigned short* A0 = xb + ((size_t)(b * 128 + w * 32 + lr)) * 512 + 8 * lg;
    const unsigned short* Bb = wb + (size_t)s * 262144 + 8 * lg;
    f32x4 acc[2][2] = {};
    for (int kb = 0; kb < 512; kb += 32) {
        BF8 a0, a1;
        a0.u = *(const u16x8*)(A0 + kb);
        a1.u = *(const u16x8*)(A0 + 16 * 512 + kb);
        #pragma unroll
        for (int nt = 0; nt < 2; nt++) {
            BF8 bf; bf.u = *(const u16x8*)(Bb + (size_t)(t0 + nt * 16 + lr) * 512 + kb);
            acc[0][nt] = __builtin_amdgcn_mfma_f32_16x16x32_bf16(a0.b, bf.b, acc[0][nt], 0, 0, 0);
            acc[1][nt] = __builtin_amdgcn_mfma_f32_16x16x32_bf16(a1.b, bf.b, acc[1][nt], 0, 0, 0);
        }
    }
    const float* bg = b_sub + (size_t)s * TT;
    #pragma unroll
    for (int nt = 0; nt < 2; nt++) {
        int t = t0 + nt * 16 + lr;
        if (t < TT) {
            float bias = bg[t];
            #pragma unroll
            for (int mt = 0; mt < 2; mt++) {
                int crow = w * 32 + mt * 16 + 4 * lg;
                #pragma unroll
                for (int r = 0; r < 4; r++) {
                    int c = crow + r;
                    if (c < CC) oute[((size_t)b * CC + c) * TT + t] = acc[mt][nt][r] + bias;
                }
            }
        }
    }
}

// ---------------- fused FIR+conv2 (round-0 verbatim) ----------------
__global__ __launch_bounds__(384) void k_fc(const float* __restrict__ oute,
                                            const unsigned short* __restrict__ wcb,
                                            const float* __restrict__ b1f,
                                            const unsigned short* __restrict__ w2p,
                                            float* __restrict__ part) {
    __shared__ float e2[2][512];
    __shared__ unsigned short pt[96][164];
    int chunk = blockIdx.x, b = blockIdx.y;
    int tid = threadIdx.x, w = tid >> 6, l = tid & 63, lr = l & 15, lg = l >> 4;
    BF8 af[5]; float4 bf4[5];
    #pragma unroll
    for (int ot = 0; ot < 5; ot++) {
        af[ot].u = *(const u16x8*)(wcb + (ot * 16 + lr) * 32 + 8 * lg);
        bf4[ot] = *(const float4*)(b1f + ot * 16 + 4 * lg);
    }
    const unsigned short* Arow = w2p + (size_t)lr * KP + 8 * lg;
    f32x4 acc2[5] = {};
    for (int ci = 0; ci < 4; ci++) {
        int cp = chunk * 4 + ci;
        bool live = cp < 61;              // block-uniform
        if (live) {
            if (tid < 250) {
                int cc = tid / 125, i = tid % 125;
                ((float4*)e2[cc])[i] = ((const float4*)(oute + ((size_t)b * CC + cp * 2 + cc) * TT))[i];
            }
            if (tid >= 232 && tid < 256) {   // zero-pad e[500..511] both rows
                int j = tid - 232; int cc = j / 12, i = 500 + (j % 12);
                e2[cc][i] = 0.f;
            }
        }
        __syncthreads();                  // e2 ready; prev-iter pt reads done
        if (live) {
            #pragma unroll
            for (int cc = 0; cc < 2; cc++) {
                int t = w * 16 + lr;
                const float* ew = e2[cc] + 5 * t + 8 * lg;
                BF8 bfr;
                #pragma unroll
                for (int j = 0; j < 8; j++) bfr.u[j] = f2bf(ew[j]);
                f32x4 fa[5] = {};
                #pragma unroll
                for (int ot = 0; ot < 5; ot++)
                    fa[ot] = __builtin_amdgcn_mfma_f32_16x16x32_bf16(af[ot].b, bfr.b, fa[ot], 0, 0, 0);
                #pragma unroll
                for (int ot = 0; ot < 5; ot++) {
                    union { unsigned short s[4]; uint2 v; } pk;
                    #pragma unroll
                    for (int r = 0; r < 4; r++) pk.s[r] = f2bf(eluf(fa[ot][r] + bf4[ot][r]));
                    *(uint2*)&pt[t][cc * 80 + ot * 16 + 4 * lg] = pk.v;
                }
            }
        }
        __syncthreads();                  // pt ready
        if (live) {
            #pragma unroll
            for (int kl = 0; kl < 5; kl++) {
                BF8 bf; bf.u = *(const u16x8*)(&pt[w * 16 + lr][kl * 32 + lg * 8]);
                int ko = cp * 160 + kl * 32;
                #pragma unroll
                for (int mt = 0; mt < 5; mt++) {
                    BF8 a; a.u = *(const u16x8*)(Arow + (size_t)mt * 16 * KP + ko);
                    acc2[mt] = __builtin_amdgcn_mfma_f32_16x16x32_bf16(a.b, bf.b, acc2[mt], 0, 0, 0);
                }
            }
        }
    }
    float* pp = part + ((size_t)(chunk * BB + b) * WID) * TP;
    int t = w * 16 + lr;
    #pragma unroll
    for (int mt = 0; mt < 5; mt++) {
        int ob = mt * 16 + 4 * lg;
        #pragma unroll
        for (int r = 0; r < 4; r++)
            pp[(size_t)(ob + r) * TP + t] = acc2[mt][r];
    }
}

// ---------------- reduce split-K + bn2 + elu + proj -> z_bf ----------------
// 256 blocks (8 t-groups x 32 b); part reads fully float4-vectorized.
__global__ __launch_bounds__(256) void k_redproj(const float* __restrict__ part,
                                                 const float* __restrict__ scale2,
                                                 const float* __restrict__ shift2f,
                                                 const float* __restrict__ pw,
                                                 const float* __restrict__ pb,
                                                 unsigned short* __restrict__ zbf) {
    __shared__ float ly[WID * 12];   // 960
    __shared__ float lw[EMB * WID];  // 640
    int tq = blockIdx.x, b = blockIdx.y;
    int tid = threadIdx.x;
    int t0 = tq * 12;
    for (int i = tid; i < EMB * WID; i += 256) lw[i] = pw[i];
    if (tid < 240) {                 // 80 o x 3 float4
        int o = tid / 3, q = tid % 3;
        const float* pbase = part + (size_t)b * (WID * TP) + o * TP + t0 + 4 * q;
        float4 a = {0.f, 0.f, 0.f, 0.f};
        #pragma unroll
        for (int ks = 0; ks < KSPLIT; ks++) {
            float4 v = *(const float4*)(pbase + (size_t)ks * (BB * WID * TP));
            a.x += v.x; a.y += v.y; a.z += v.z; a.w += v.w;
        }
        float sc = scale2[o], sh = shift2f[o];
        ly[o * 12 + 4 * q + 0] = eluf(a.x * sc + sh);
        ly[o * 12 + 4 * q + 1] = eluf(a.y * sc + sh);
        ly[o * 12 + 4 * q + 2] = eluf(a.z * sc + sh);
        ly[o * 12 + 4 * q + 3] = eluf(a.w * sc + sh);
    }
    __syncthreads();
    if (tid < 12 * EMB) {
        int e = tid & 7, tl = tid >> 3;
        float acc = pb[e];
        #pragma unroll 10
        for (int o = 0; o < WID; o++) acc = fmaf(ly[o * 12 + tl], lw[e * WID + o], acc);
        zbf[(size_t)b * HID + (t0 + tl) * EMB + e] = f2bf(acc);
    }
}

// ---------------- mlp1: 128 blocks (64 col-units x 2 row-halves); 4-wave K-split ----
__global__ __launch_bounds__(256) void k_mlp1(const unsigned short* __restrict__ zbf,
                                              const unsigned short* __restrict__ w1b,
                                              const float* __restrict__ bias,
                                              float* __restrict__ z1,
                                              unsigned short* __restrict__ gbf) {
    __shared__ float accb[4][64][4];
    int cu = blockIdx.x >> 1, rh = blockIdx.x & 1;
    int tid = threadIdx.x, w = tid >> 6, l = tid & 63, lr = l & 15, lg = l >> 4;
    int pcol = cu * 16 + lr;
    const unsigned short* wr = w1b + (size_t)pcol * HID + w * 192 + 8 * lg;
    const unsigned short* za = zbf + (size_t)(rh * 16 + lr) * HID + w * 192 + 8 * lg;
    f32x4 acc = {};
    #pragma unroll
    for (int kb = 0; kb < 192; kb += 32) {
        BF8 bf; bf.u = *(const u16x8*)(wr + kb);
        BF8 a;  a.u  = *(const u16x8*)(za + kb);
        acc = __builtin_amdgcn_mfma_f32_16x16x32_bf16(a.b, bf.b, acc, 0, 0, 0);
    }
    #pragma unroll
    for (int r = 0; r < 4; r++) accb[w][l][r] = acc[r];
    __syncthreads();
    if (w == 0) {
        float bs = bias[pcol];
        #pragma unroll
        for (int r = 0; r < 4; r++) {
            int row = rh * 16 + 4 * lg + r;
            float v = bs;
            #pragma unroll
            for (int q = 0; q < 4; q++) v += accb[q][l][r];
            z1[(size_t)row * PROJ + pcol] = v;
            gbf[(size_t)row * PROJ + pcol] = f2bf(0.5f * v * (1.f + erff(v * 0.70710678118654752f)));
        }
    }
}

// ---------------- mlp2: 128 blocks; y = z1 + Gbf @ W2b^T + b2; 4-wave K-split ----
__global__ __launch_bounds__(256) void k_mlp2(const unsigned short* __restrict__ gbf,
                                              const float* __restrict__ z1,
                                              const unsigned short* __restrict__ w2b,
                                              const float* __restrict__ bias,
                                              float* __restrict__ y) {
    __shared__ float accb[4][64][4];
    int cu = blockIdx.x >> 1, rh = blockIdx.x & 1;
    int tid = threadIdx.x, w = tid >> 6, l = tid & 63, lr = l & 15, lg = l >> 4;
    int pc = cu * 16 + lr;
    const unsigned short* wr = w2b + (size_t)pc * PROJ + w * 256 + 8 * lg;
    const unsigned short* ga = gbf + (size_t)(rh * 16 + lr) * PROJ + w * 256 + 8 * lg;
    f32x4 acc = {};
    #pragma unroll
    for (int kb = 0; kb < 256; kb += 32) {
        BF8 bf; bf.u = *(const u16x8*)(wr + kb);
        BF8 a;  a.u  = *(const u16x8*)(ga + kb);
        acc = __builtin_amdgcn_mfma_f32_16x16x32_bf16(a.b, bf.b, acc, 0, 0, 0);
    }
    #pragma unroll
    for (int r = 0; r < 4; r++) accb[w][l][r] = acc[r];
    __syncthreads();
    if (w == 0) {
        float bs = bias[pc];
        #pragma unroll
        for (int r = 0; r < 4; r++) {
            int row = rh * 16 + 4 * lg + r;
            float v = bs + z1[(size_t)row * PROJ + pc];
            #pragma unroll
            for (int q = 0; q < 4; q++) v += accb[q][l][r];
            y[(size_t)row * PROJ + pc] = v;
        }
    }
}

// ---------------- LayerNorm over 1024 per row -> d_out (round-0 verbatim) ----------------
__global__ __launch_bounds__(256) void k_ln(const float* __restrict__ y,
                                            const float* __restrict__ lg,
                                            const float* __restrict__ lb,
                                            float* __restrict__ out) {
    int b = blockIdx.x, tid = threadIdx.x;
    const float4* yr = (const float4*)(y + (size_t)b * PROJ);
    float4 v = yr[tid];
    float s  = v.x + v.y + v.z + v.w;
    float sq = v.x*v.x + v.y*v.y + v.z*v.z + v.w*v.w;
    #pragma unroll
    for (int off = 32; off > 0; off >>= 1) {
        s  += __shfl_down(s, off);
        sq += __shfl_down(sq, off);
    }
    __shared__ float ss[4], ssq[4];
    int wv = tid >> 6, lane = tid & 63;
    if (lane == 0) { ss[wv] = s; ssq[wv] = sq; }
    __syncthreads();
    __shared__ float smu, sinv;
    if (tid == 0) {
        float Sm = ss[0] + ss[1] + ss[2] + ss[3];
        float Sq = ssq[0] + ssq[1] + ssq[2] + ssq[3];
        float mu = Sm * (1.f / PROJ);
        float var = Sq * (1.f / PROJ) - mu * mu;
        smu = mu;
        sinv = rsqrtf(var + EPSF);
    }
    __syncthreads();
    float mu = smu, inv = sinv;
    float4 g4 = ((const float4*)lg)[tid];
    float4 b4 = ((const float4*)lb)[tid];
    float4 o4;
    o4.x = (v.x - mu) * inv * g4.x + b4.x;
    o4.y = (v.y - mu) * inv * g4.y + b4.y;
    o4.z = (v.z - mu) * inv * g4.z + b4.z;
    o4.w = (v.w - mu) * inv * g4.w + b4.w;
    ((float4*)(out + (size_t)b * PROJ))[tid] = o4;
}

extern "C" void kernel_launch(void* const* d_in, const int* in_sizes, int n_in,
                              void* d_out, int out_size, void* d_ws, size_t ws_size,
                              hipStream_t stream) {
    const float* x        = (const float*)d_in[0];
    const int*   sid      = (const int*)  d_in[1];
    const float* W_sub    = (const float*)d_in[2];
    const float* b_sub    = (const float*)d_in[3];
    const float* conv1_w  = (const float*)d_in[4];
    const float* conv1_b  = (const float*)d_in[5];
    const float* bn1_g    = (const float*)d_in[6];
    const float* bn1_b    = (const float*)d_in[7];
    const float* bn1_m    = (const float*)d_in[8];
    const float* bn1_v    = (const float*)d_in[9];
    const float* conv2_w  = (const float*)d_in[10];
    const float* conv2_b  = (const float*)d_in[11];
    const float* bn2_g    = (const float*)d_in[12];
    const float* bn2_b    = (const float*)d_in[13];
    const float* bn2_m    = (const float*)d_in[14];
    const float* bn2_v    = (const float*)d_in[15];
    const float* proj_w   = (const float*)d_in[16];
    const float* proj_b   = (const float*)d_in[17];
    const float* mlp1_w   = (const float*)d_in[18];
    const float* mlp1_b   = (const float*)d_in[19];
    const float* mlp2_w   = (const float*)d_in[20];
    const float* mlp2_b   = (const float*)d_in[21];
    const float* ln_g     = (const float*)d_in[22];
    const float* ln_b     = (const float*)d_in[23];
    float* out = (float*)d_out;
    float* ws  = (float*)d_ws;

    float* ws_e    = ws + OFF_E;
    unsigned short* ws_xb  = (unsigned short*)(ws + OFF_XB);
    unsigned short* ws_wb  = (unsigned short*)(ws + OFF_WB);
    unsigned short* ws_w2p = (unsigned short*)(ws + OFF_W2P);
    float* ws_part = ws + OFF_PART;
    unsigned short* ws_zbf = (unsigned short*)(ws + OFF_Z);
    float* ws_z1   = ws + OFF_Z1;
    unsigned short* ws_gbf = (unsigned short*)(ws + OFF_G);
    float* ws_y    = ws + OFF_Y;
    unsigned short* ws_w1b = (unsigned short*)(ws + OFF_W1B);
    unsigned short* ws_w2b = (unsigned short*)(ws + OFF_W2B);
    unsigned short* ws_wcb = (unsigned short*)(ws + OFF_WCB);
    float* ws_b1f  = ws + OFF_B1F;
    float* ws_sc2  = ws + OFF_SC2;
    float* ws_sh2  = ws + OFF_SH2;

    hipLaunchKernelGGL(k_pack, dim3((NPK_TOT + 255) / 256), dim3(256), 0, stream,
                       x, W_sub, conv2_w, mlp1_w, mlp2_w,
                       conv1_w, conv1_b, bn1_g, bn1_b, bn1_m, bn1_v,
                       conv2_b, bn2_g, bn2_b, bn2_m, bn2_v,
                       ws_xb, ws_wb, ws_w2p, ws_w1b, ws_w2b,
                       ws_wcb, ws_b1f, ws_sc2, ws_sh2);

    hipLaunchKernelGGL(k_einsum, dim3(16, BB), dim3(256), 0, stream,
                       ws_xb, ws_wb, sid, b_sub, ws_e);

    hipLaunchKernelGGL(k_fc, dim3(KSPLIT, BB), dim3(384), 0, stream,
                       ws_e, ws_wcb, ws_b1f, ws_w2p, ws_part);

    hipLaunchKernelGGL(k_redproj, dim3(8, BB), dim3(256), 0, stream,
                       ws_part, ws_sc2, ws_sh2, proj_w, proj_b, ws_zbf);

    hipLaunchKernelGGL(k_mlp1, dim3(128), dim3(256), 0, stream,
                       ws_zbf, ws_w1b, mlp1_b, ws_z1, ws_gbf);

    hipLaunchKernelGGL(k_mlp2, dim3(128), dim3(256), 0, stream,
                       ws_gbf, ws_z1, ws_w2b, mlp2_b, ws_y);

    hipLaunchKernelGGL(k_ln, dim3(BB), dim3(256), 0, stream,
                       ws_y, ln_g, ln_b, out);
}